// Round 1
// baseline (683.415 us; speedup 1.0000x reference)
//
#include <hip/hip_runtime.h>
#include <hip/hip_bf16.h>

#define N_NODES 8192
#define IN_FEAT 256
#define OUT_F   64
#define NHEAD   4
#define HF      256     // NHEAD*OUT_F
#define NEG     0.2f

typedef unsigned short u16;
typedef __attribute__((ext_vector_type(8))) short short8;   // 8 bf16 (4 VGPRs)
typedef __attribute__((ext_vector_type(4))) float f32x4;    // MFMA C/D

__device__ __forceinline__ float bf2f(u16 x) {
    union { unsigned int u; float f; } v; v.u = ((unsigned int)x) << 16; return v.f;
}
__device__ __forceinline__ u16 f2bf(float f) {
    union { unsigned int u; float f; } v; v.f = f;
    unsigned int r = v.u + 0x7FFFu + ((v.u >> 16) & 1u);  // RNE
    return (u16)(r >> 16);
}
__device__ __forceinline__ float leaky(float x) {
    return fmaxf(x, 0.f) + NEG * fminf(x, 0.f);
}

// ---------------------------------------------------------------------------
// K0: PWT[k][c] = PW[c][k]  (256x256 fp32 transpose, 16 blocks of 64x64 tiles)
// Makes the proj-weight stream coalesced in k_gemm (same pattern as W).
// ---------------------------------------------------------------------------
__global__ __launch_bounds__(256) void k_tr(const float* __restrict__ PW,
                                            float* __restrict__ PWT) {
    __shared__ float t[64][65];           // +1 pad: store/read conflict-free
    const int bx = (blockIdx.x & 3) * 64;   // k tile
    const int by = (blockIdx.x >> 2) * 64;  // c tile
    const int tx = threadIdx.x & 63;
    const int ty = threadIdx.x >> 6;
    #pragma unroll
    for (int r = ty; r < 64; r += 4)
        t[r][tx] = PW[(size_t)(by + r) * IN_FEAT + bx + tx];
    __syncthreads();
    #pragma unroll
    for (int r = ty; r < 64; r += 4)
        PWT[(size_t)(bx + r) * HF + by + tx] = t[tx][r];
}

// ---------------------------------------------------------------------------
// K1: per 8 rows: support = X@W -> suppT (TRANSPOSED, bf16: [H*64][N]),
//     f1/f2 head dots, proj = X@PWT + proj_b + bias -> d_out (fp32).
//     Thread c holds all 8 rows of column c => suppT write is ONE 16B store.
// ---------------------------------------------------------------------------
#define RPB 8
__global__ __launch_bounds__(256) void k_gemm(
    const float* __restrict__ inp,   // [N, 256]
    const float* __restrict__ W,     // [256, 256] (k-major rows)
    const float* __restrict__ U,     // [H*64] flat
    const float* __restrict__ V,     // [H*64] flat
    const float* __restrict__ Bias,  // [256]
    const float* __restrict__ PWT,   // [256 k][256 c]  (transposed proj_w)
    const float* __restrict__ PB,    // [256]
    u16*   __restrict__ suppT,       // [H*64][N] bf16  (feature-major!)
    float* __restrict__ f1,          // [H][N]
    float* __restrict__ f2,          // [H][N]
    float* __restrict__ outp)        // [N][256]  proj + bias + proj_b
{
    __shared__ __align__(16) float in_lds[RPB][IN_FEAT];
    const int c  = threadIdx.x;            // output column 0..255
    const int n0 = blockIdx.x * RPB;

    #pragma unroll
    for (int r = 0; r < RPB; ++r)
        in_lds[r][c] = inp[(size_t)(n0 + r) * IN_FEAT + c];
    __syncthreads();

    float accs[RPB], accp[RPB];
    #pragma unroll
    for (int r = 0; r < RPB; ++r) { accs[r] = 0.f; accp[r] = 0.f; }

    #pragma unroll 2
    for (int k = 0; k < IN_FEAT; k += 4) {
        const float w0 = W[(k + 0) * HF + c];
        const float w1 = W[(k + 1) * HF + c];
        const float w2 = W[(k + 2) * HF + c];
        const float w3 = W[(k + 3) * HF + c];
        const float p0 = PWT[(k + 0) * HF + c];
        const float p1 = PWT[(k + 1) * HF + c];
        const float p2 = PWT[(k + 2) * HF + c];
        const float p3 = PWT[(k + 3) * HF + c];
        #pragma unroll
        for (int r = 0; r < RPB; ++r) {
            const float4 xv = *(const float4*)&in_lds[r][k];
            accs[r] = fmaf(xv.x, w0, accs[r]);
            accs[r] = fmaf(xv.y, w1, accs[r]);
            accs[r] = fmaf(xv.z, w2, accs[r]);
            accs[r] = fmaf(xv.w, w3, accs[r]);
            accp[r] = fmaf(xv.x, p0, accp[r]);
            accp[r] = fmaf(xv.y, p1, accp[r]);
            accp[r] = fmaf(xv.z, p2, accp[r]);
            accp[r] = fmaf(xv.w, p3, accp[r]);
        }
    }

    const int h = c >> 6, lane = c & 63;
    const float uv = U[c], vv = V[c];
    const float bb = Bias[c] + PB[c];

    // transposed support write: one 16B store (8 rows of column c)
    union { short8 v; u16 s[8]; } sv;
    #pragma unroll
    for (int r = 0; r < RPB; ++r) sv.s[r] = f2bf(accs[r]);
    *(short8*)(suppT + (size_t)c * N_NODES + n0) = sv.v;

    #pragma unroll
    for (int r = 0; r < RPB; ++r) {
        float s1 = accs[r] * uv, s2 = accs[r] * vv;
        #pragma unroll
        for (int mm = 32; mm > 0; mm >>= 1) {
            s1 += __shfl_xor(s1, mm);
            s2 += __shfl_xor(s2, mm);
        }
        if (lane == 0) {
            f1[h * N_NODES + n0 + r] = s1;
            f2[h * N_NODES + n0 + r] = s2;
        }
        outp[(size_t)(n0 + r) * HF + c] = accp[r] + bb;
    }
}

// ---------------------------------------------------------------------------
// K2: per-head global max of f1 (upper bound for softmax shift)
// ---------------------------------------------------------------------------
__global__ __launch_bounds__(256) void k_f1max(const float* __restrict__ f1,
                                               float* __restrict__ f1max) {
    __shared__ float red[256];
    const int h = blockIdx.x;
    float m = -1e30f;
    for (int j = threadIdx.x; j < N_NODES; j += 256)
        m = fmaxf(m, f1[h * N_NODES + j]);
    red[threadIdx.x] = m;
    __syncthreads();
    for (int s = 128; s > 0; s >>= 1) {
        if (threadIdx.x < s) red[threadIdx.x] = fmaxf(red[threadIdx.x], red[threadIdx.x + s]);
        __syncthreads();
    }
    if (threadIdx.x == 0) f1max[h] = red[0];
}

// ---------------------------------------------------------------------------
// K3: MFMA attention. One block per 16-row i-tile; wave w = head w.
//   B fragment now comes from suppT: 8 contiguous u16 along j per (col,t)
//   -> one dwordx4 load per n-tile instead of 8 scalar ushort gathers.
// ---------------------------------------------------------------------------
#define TI 16
__global__ __launch_bounds__(256) void k_attn_mfma(
    const float* __restrict__ adj,   // [N, N] fp32
    const u16* __restrict__ suppT,   // [H*64][N] bf16 (feature-major)
    const float* __restrict__ f1,    // [H][N]
    const float* __restrict__ f2,    // [H][N]
    const float* __restrict__ f1max, // [H]
    float* __restrict__ out)         // [N][256] fp32: proj in, proj+attn out
{
    // nibble flags: byte b of row i holds j=4b..4b+3 at bits 0..3.
    __shared__ u16 abits[TI][1026];   // ~32.8 KB

    const int i0   = blockIdx.x * TI;
    const int tid  = threadIdx.x;
    const int wv   = tid >> 6;        // wave = head
    const int lane = tid & 63;
    const int col  = lane & 15;       // m (A) / n (B) / col (C)
    const int quad = lane >> 4;

    // ---- Phase 1: stage adjacency flags (wave wv does rows 4wv..4wv+3) ----
    #pragma unroll
    for (int rr = 0; rr < 4; ++rr) {
        const int r = (wv << 2) + rr;
        const float* ar = adj + (size_t)(i0 + r) * N_NODES;
        #pragma unroll 2
        for (int it = 0; it < 16; ++it) {
            const int j = it * 512 + lane * 8;
            const float4 a0 = *(const float4*)(ar + j);
            const float4 a1 = *(const float4*)(ar + j + 4);
            const unsigned v =
                (unsigned)(a0.x != 0.f)        | ((unsigned)(a0.y != 0.f) << 1) |
                ((unsigned)(a0.z != 0.f) << 2) | ((unsigned)(a0.w != 0.f) << 3) |
                ((unsigned)(a1.x != 0.f) << 8) | ((unsigned)(a1.y != 0.f) << 9) |
                ((unsigned)(a1.z != 0.f) << 10)| ((unsigned)(a1.w != 0.f) << 11);
            abits[r][it * 64 + lane] = (u16)v;
        }
    }
    __syncthreads();

    // ---- Phase 2: flash j-loop ----
    const int h = wv;
    const float* f1h = f1 + (size_t)h * N_NODES;
    const float f2i  = f2[(size_t)h * N_NODES + i0 + col];      // i = col
    const float mi   = leaky(f1max[h] + f2i);                   // >= row max
    // B base: row (h*64 + col), n-tiles step 16 rows
    const u16* bt = suppT + (size_t)((h << 6) + col) * N_NODES;

    f32x4 acc[4];
    #pragma unroll
    for (int t = 0; t < 4; ++t) acc[t] = (f32x4){0.f, 0.f, 0.f, 0.f};
    float lsum = 0.f;

    for (int jb = 0; jb < N_NODES; jb += 32) {
        const int jq = jb + (quad << 3);                        // this lane's j base
        const float4 fa = *(const float4*)(f1h + jq);
        const float4 fb = *(const float4*)(f1h + jq + 4);
        const u16 bw = abits[col][(jb >> 3) + quad];            // 8 flag bits

        float fj[8] = {fa.x, fa.y, fa.z, fa.w, fb.x, fb.y, fb.z, fb.w};
        union { short8 v; u16 s[8]; } af;
        #pragma unroll
        for (int jj = 0; jj < 8; ++jj) {
            const float t0 = fj[jj] + f2i;
            const float lw = fmaxf(t0, 0.f) + NEG * fminf(t0, 0.f);
            const int sh_jj = (jj & 3) + ((jj >> 2) << 3);
            const float e = ((bw >> sh_jj) & 1) ? __expf(lw - mi) : 0.f;
            lsum += e;
            af.s[jj] = f2bf(e);
        }

        #pragma unroll
        for (int t = 0; t < 4; ++t) {
            const short8 bv = *(const short8*)(bt + (size_t)(t << 4) * N_NODES + jq);
            acc[t] = __builtin_amdgcn_mfma_f32_16x16x32_bf16(af.v, bv, acc[t], 0, 0, 0);
        }
    }

    // denominator: reduce over quads (each quad summed its own k-slice)
    lsum += __shfl_xor(lsum, 16);
    lsum += __shfl_xor(lsum, 32);   // now lane L holds lsum for i = L&15

    // ---- epilogue: divide + add onto proj in d_out ----
    #pragma unroll
    for (int reg = 0; reg < 4; ++reg) {
        const int irow = (quad << 2) + reg;                     // C-layout row
        const float inv = 1.f / __shfl(lsum, irow);
        float* op = out + (size_t)(i0 + irow) * HF + (h << 6) + col;
        #pragma unroll
        for (int t = 0; t < 4; ++t) op[t << 4] += acc[t][reg] * inv;
    }
}

// ---------------------------------------------------------------------------
extern "C" void kernel_launch(void* const* d_in, const int* in_sizes, int n_in,
                              void* d_out, int out_size, void* d_ws, size_t ws_size,
                              hipStream_t stream) {
    const float* inp  = (const float*)d_in[0];  // [8192,256]
    const float* adj  = (const float*)d_in[1];  // [8192,8192]
    const float* W    = (const float*)d_in[2];  // [256,256]
    const float* U    = (const float*)d_in[3];  // [4,64,1]
    const float* V    = (const float*)d_in[4];  // [4,64,1]
    const float* Bias = (const float*)d_in[5];  // [1,256]
    const float* PW   = (const float*)d_in[6];  // [256,256]
    const float* PB   = (const float*)d_in[7];  // [256]
    float* out = (float*)d_out;                 // [8192,256] fp32

    char* ws = (char*)d_ws;
    u16*   suppT = (u16*)(ws);                                   // 4 MiB  [H*64][N]
    float* f1    = (float*)(ws + (4u << 20));                    // 128 KiB
    float* f2    = (float*)(ws + (4u << 20) + (128u << 10));     // 128 KiB
    float* f1mx  = (float*)(ws + (4u << 20) + (256u << 10));     // 16 B
    float* PWT   = (float*)(ws + (4u << 20) + (320u << 10));     // 256 KiB

    k_tr<<<16, 256, 0, stream>>>(PW, PWT);
    k_gemm<<<N_NODES / RPB, 256, 0, stream>>>(inp, W, U, V, Bias, PWT, PB,
                                              suppT, f1, f2, out);
    k_f1max<<<NHEAD, 256, 0, stream>>>(f1, f1mx);
    k_attn_mfma<<<N_NODES / TI, 256, 0, stream>>>(adj, suppT, f1, f2, f1mx, out);
}

// Round 2
// 675.323 us; speedup vs baseline: 1.0120x; 1.0120x over previous
//
#include <hip/hip_runtime.h>
#include <hip/hip_bf16.h>

#define N_NODES 8192
#define IN_FEAT 256
#define OUT_F   64
#define NHEAD   4
#define HF      256     // NHEAD*OUT_F
#define NEG     0.2f

typedef unsigned short u16;
typedef __attribute__((ext_vector_type(8))) short short8;   // 8 bf16 (4 VGPRs)
typedef __attribute__((ext_vector_type(4))) float f32x4;    // MFMA C/D

__device__ __forceinline__ float bf2f(u16 x) {
    union { unsigned int u; float f; } v; v.u = ((unsigned int)x) << 16; return v.f;
}
__device__ __forceinline__ u16 f2bf(float f) {
    union { unsigned int u; float f; } v; v.f = f;
    unsigned int r = v.u + 0x7FFFu + ((v.u >> 16) & 1u);  // RNE
    return (u16)(r >> 16);
}
__device__ __forceinline__ float leaky(float x) {
    return fmaxf(x, 0.f) + NEG * fminf(x, 0.f);
}

// ---------------------------------------------------------------------------
// K0: PWT[k][c] = PW[c][k]  (256x256 fp32 transpose)
// ---------------------------------------------------------------------------
__global__ __launch_bounds__(256) void k_tr(const float* __restrict__ PW,
                                            float* __restrict__ PWT) {
    __shared__ float t[64][65];
    const int bx = (blockIdx.x & 3) * 64;   // k tile
    const int by = (blockIdx.x >> 2) * 64;  // c tile
    const int tx = threadIdx.x & 63;
    const int ty = threadIdx.x >> 6;
    #pragma unroll
    for (int r = ty; r < 64; r += 4)
        t[r][tx] = PW[(size_t)(by + r) * IN_FEAT + bx + tx];
    __syncthreads();
    #pragma unroll
    for (int r = ty; r < 64; r += 4)
        PWT[(size_t)(bx + r) * HF + by + tx] = t[tx][r];
}

// ---------------------------------------------------------------------------
// K1: per 8 rows: support = X@W -> suppT (bf16 [H*64][N]), f1/f2 head dots,
//     proj = X@PWT + proj_b + bias -> d_out (fp32).
//     Inner loop: register-prefetch next k-group of W/PWT (distance 1 body
//     = ~512 VALU cycles, covers L2 latency).
// ---------------------------------------------------------------------------
#define RPB 8
__global__ __launch_bounds__(256) void k_gemm(
    const float* __restrict__ inp,   // [N, 256]
    const float* __restrict__ W,     // [256, 256] (k-major rows)
    const float* __restrict__ U,     // [H*64] flat
    const float* __restrict__ V,     // [H*64] flat
    const float* __restrict__ Bias,  // [256]
    const float* __restrict__ PWT,   // [256 k][256 c]  (transposed proj_w)
    const float* __restrict__ PB,    // [256]
    u16*   __restrict__ suppT,       // [H*64][N] bf16  (feature-major)
    float* __restrict__ f1,          // [H][N]
    float* __restrict__ f2,          // [H][N]
    float* __restrict__ outp)        // [N][256]  proj + bias + proj_b
{
    __shared__ __align__(16) float in_lds[RPB][IN_FEAT];
    const int c  = threadIdx.x;            // output column 0..255
    const int n0 = blockIdx.x * RPB;

    #pragma unroll
    for (int r = 0; r < RPB; ++r)
        in_lds[r][c] = inp[(size_t)(n0 + r) * IN_FEAT + c];
    __syncthreads();

    float accs[RPB], accp[RPB];
    #pragma unroll
    for (int r = 0; r < RPB; ++r) { accs[r] = 0.f; accp[r] = 0.f; }

    const float* wc = W   + c;
    const float* pc = PWT + c;
    float w0 = wc[0 * HF], w1 = wc[1 * HF], w2 = wc[2 * HF], w3 = wc[3 * HF];
    float p0 = pc[0 * HF], p1 = pc[1 * HF], p2 = pc[2 * HF], p3 = pc[3 * HF];

    #pragma unroll 1
    for (int k = 0; k < IN_FEAT; k += 4) {
        const int kn = (k + 4) & 255;          // wrap: last prefetch discarded
        const float nw0 = wc[(kn + 0) * HF];
        const float nw1 = wc[(kn + 1) * HF];
        const float nw2 = wc[(kn + 2) * HF];
        const float nw3 = wc[(kn + 3) * HF];
        const float np0 = pc[(kn + 0) * HF];
        const float np1 = pc[(kn + 1) * HF];
        const float np2 = pc[(kn + 2) * HF];
        const float np3 = pc[(kn + 3) * HF];
        #pragma unroll
        for (int r = 0; r < RPB; ++r) {
            const float4 xv = *(const float4*)&in_lds[r][k];
            accs[r] = fmaf(xv.x, w0, accs[r]);
            accs[r] = fmaf(xv.y, w1, accs[r]);
            accs[r] = fmaf(xv.z, w2, accs[r]);
            accs[r] = fmaf(xv.w, w3, accs[r]);
            accp[r] = fmaf(xv.x, p0, accp[r]);
            accp[r] = fmaf(xv.y, p1, accp[r]);
            accp[r] = fmaf(xv.z, p2, accp[r]);
            accp[r] = fmaf(xv.w, p3, accp[r]);
        }
        w0 = nw0; w1 = nw1; w2 = nw2; w3 = nw3;
        p0 = np0; p1 = np1; p2 = np2; p3 = np3;
    }

    const int h = c >> 6, lane = c & 63;
    const float uv = U[c], vv = V[c];
    const float bb = Bias[c] + PB[c];

    // transposed support write: one 16B store (8 rows of column c)
    union { short8 v; u16 s[8]; } sv;
    #pragma unroll
    for (int r = 0; r < RPB; ++r) sv.s[r] = f2bf(accs[r]);
    *(short8*)(suppT + (size_t)c * N_NODES + n0) = sv.v;

    #pragma unroll
    for (int r = 0; r < RPB; ++r) {
        float s1 = accs[r] * uv, s2 = accs[r] * vv;
        #pragma unroll
        for (int mm = 32; mm > 0; mm >>= 1) {
            s1 += __shfl_xor(s1, mm);
            s2 += __shfl_xor(s2, mm);
        }
        if (lane == 0) {
            f1[h * N_NODES + n0 + r] = s1;
            f2[h * N_NODES + n0 + r] = s2;
        }
        outp[(size_t)(n0 + r) * HF + c] = accp[r] + bb;
    }
}

// ---------------------------------------------------------------------------
// K2: per-head global max of f1 (upper bound for softmax shift)
// ---------------------------------------------------------------------------
__global__ __launch_bounds__(256) void k_f1max(const float* __restrict__ f1,
                                               float* __restrict__ f1max) {
    __shared__ float red[256];
    const int h = blockIdx.x;
    float m = -1e30f;
    for (int j = threadIdx.x; j < N_NODES; j += 256)
        m = fmaxf(m, f1[h * N_NODES + j]);
    red[threadIdx.x] = m;
    __syncthreads();
    for (int s = 128; s > 0; s >>= 1) {
        if (threadIdx.x < s) red[threadIdx.x] = fmaxf(red[threadIdx.x], red[threadIdx.x + s]);
        __syncthreads();
    }
    if (threadIdx.x == 0) f1max[h] = red[0];
}

// ---------------------------------------------------------------------------
// K3: MFMA attention, 1024-thread blocks: 16 waves = 4 heads x 4 j-chunks.
//   One block per 16-row i-tile. Adjacency flags staged once in LDS, shared
//   by all 16 waves. Each wave flash-loops over its 2048-j chunk; chunk
//   partials (acc + lsum) combined through LDS (overlaid on abits).
//   Occupancy: LDS 67.6 KB -> 2 blocks/CU = 32 waves/CU (vs 8 before).
// ---------------------------------------------------------------------------
#define TI 16
#define JSPLIT 4
#define JCHUNK (N_NODES / JSPLIT)   // 2048

union AttnSMem {
    u16   abits[TI][1026];             // 32.8 KB: nibble flags, full 8192 j
    float red[NHEAD][JSPLIT][TI][65];  // 66.6 KB: chunk partial numerators
};

__global__ __launch_bounds__(1024, 8) void k_attn_mfma(
    const float* __restrict__ adj,   // [N, N] fp32
    const u16* __restrict__ suppT,   // [H*64][N] bf16 (feature-major)
    const float* __restrict__ f1,    // [H][N]
    const float* __restrict__ f2,    // [H][N]
    const float* __restrict__ f1max, // [H]
    float* __restrict__ out)         // [N][256] fp32: proj in, proj+attn out
{
    __shared__ AttnSMem sm;
    __shared__ float den[NHEAD][JSPLIT][TI];

    const int i0   = blockIdx.x * TI;
    const int tid  = threadIdx.x;
    const int wv   = tid >> 6;        // 0..15
    const int lane = tid & 63;
    const int col  = lane & 15;       // m (A) / n (B) / col (C)
    const int quad = lane >> 4;

    // ---- Phase 1: stage adjacency flags (wave wv stages row wv) ----
    {
        const int r = wv;
        const float* ar = adj + (size_t)(i0 + r) * N_NODES;
        #pragma unroll 2
        for (int it = 0; it < 16; ++it) {
            const int j = it * 512 + lane * 8;
            const float4 a0 = *(const float4*)(ar + j);
            const float4 a1 = *(const float4*)(ar + j + 4);
            const unsigned v =
                (unsigned)(a0.x != 0.f)        | ((unsigned)(a0.y != 0.f) << 1) |
                ((unsigned)(a0.z != 0.f) << 2) | ((unsigned)(a0.w != 0.f) << 3) |
                ((unsigned)(a1.x != 0.f) << 8) | ((unsigned)(a1.y != 0.f) << 9) |
                ((unsigned)(a1.z != 0.f) << 10)| ((unsigned)(a1.w != 0.f) << 11);
            sm.abits[r][it * 64 + lane] = (u16)v;
        }
    }
    __syncthreads();

    // ---- Phase 2: flash j-loop over this wave's chunk ----
    const int h  = wv & 3;            // head
    const int jc = wv >> 2;           // j-chunk 0..3
    const float* f1h = f1 + (size_t)h * N_NODES;
    const float f2i  = f2[(size_t)h * N_NODES + i0 + col];      // i = col
    const float mi   = leaky(f1max[h] + f2i);                   // >= row max
    const u16* bt = suppT + (size_t)((h << 6) + col) * N_NODES; // B base row

    f32x4 acc[4];
    #pragma unroll
    for (int t = 0; t < 4; ++t) acc[t] = (f32x4){0.f, 0.f, 0.f, 0.f};
    float lsum = 0.f;

    const int jend = jc * JCHUNK + JCHUNK;
    for (int jb = jc * JCHUNK; jb < jend; jb += 32) {
        const int jq = jb + (quad << 3);                        // this lane's j base
        const float4 fa = *(const float4*)(f1h + jq);
        const float4 fb = *(const float4*)(f1h + jq + 4);
        const u16 bw = sm.abits[col][(jb >> 3) + quad];         // 8 flag bits

        float fj[8] = {fa.x, fa.y, fa.z, fa.w, fb.x, fb.y, fb.z, fb.w};
        union { short8 v; u16 s[8]; } af;
        #pragma unroll
        for (int jj = 0; jj < 8; ++jj) {
            const float t0 = fj[jj] + f2i;
            const float lw = fmaxf(t0, 0.f) + NEG * fminf(t0, 0.f);
            const int sh_jj = (jj & 3) + ((jj >> 2) << 3);
            const float e = ((bw >> sh_jj) & 1) ? __expf(lw - mi) : 0.f;
            lsum += e;
            af.s[jj] = f2bf(e);
        }

        #pragma unroll
        for (int t = 0; t < 4; ++t) {
            const short8 bv = *(const short8*)(bt + (size_t)(t << 4) * N_NODES + jq);
            acc[t] = __builtin_amdgcn_mfma_f32_16x16x32_bf16(af.v, bv, acc[t], 0, 0, 0);
        }
    }

    // chunk-partial denominator: reduce over quads
    lsum += __shfl_xor(lsum, 16);
    lsum += __shfl_xor(lsum, 32);   // lane L holds chunk lsum for i = L&15

    // ---- Phase 3: combine chunk partials through LDS ----
    __syncthreads();                 // all abits reads complete (red overlays)

    if (lane < 16) den[h][jc][lane] = lsum;
    #pragma unroll
    for (int reg = 0; reg < 4; ++reg) {
        const int irow = (quad << 2) + reg;                     // C-layout row
        #pragma unroll
        for (int t = 0; t < 4; ++t)
            sm.red[h][jc][irow][(t << 4) | col] = acc[t][reg];
    }
    __syncthreads();

    // final reduce + store: head h handled by its 4 waves (256 threads)
    const int gid = (jc << 6) | lane;    // 0..255 within head group
    const int row = gid >> 4;            // 0..15
    const int fe  = gid & 15;
    const float dsum = den[h][0][row] + den[h][1][row] + den[h][2][row] + den[h][3][row];
    const float inv = 1.f / dsum;
    float* op = out + (size_t)(i0 + row) * HF + (h << 6);
    #pragma unroll
    for (int ff = 0; ff < 4; ++ff) {
        const int feat = (ff << 4) | fe;
        const float s = sm.red[h][0][row][feat] + sm.red[h][1][row][feat]
                      + sm.red[h][2][row][feat] + sm.red[h][3][row][feat];
        op[feat] += s * inv;
    }
}

// ---------------------------------------------------------------------------
extern "C" void kernel_launch(void* const* d_in, const int* in_sizes, int n_in,
                              void* d_out, int out_size, void* d_ws, size_t ws_size,
                              hipStream_t stream) {
    const float* inp  = (const float*)d_in[0];  // [8192,256]
    const float* adj  = (const float*)d_in[1];  // [8192,8192]
    const float* W    = (const float*)d_in[2];  // [256,256]
    const float* U    = (const float*)d_in[3];  // [4,64,1]
    const float* V    = (const float*)d_in[4];  // [4,64,1]
    const float* Bias = (const float*)d_in[5];  // [1,256]
    const float* PW   = (const float*)d_in[6];  // [256,256]
    const float* PB   = (const float*)d_in[7];  // [256]
    float* out = (float*)d_out;                 // [8192,256] fp32

    char* ws = (char*)d_ws;
    u16*   suppT = (u16*)(ws);                                   // 4 MiB  [H*64][N]
    float* f1    = (float*)(ws + (4u << 20));                    // 128 KiB
    float* f2    = (float*)(ws + (4u << 20) + (128u << 10));     // 128 KiB
    float* f1mx  = (float*)(ws + (4u << 20) + (256u << 10));     // 16 B
    float* PWT   = (float*)(ws + (4u << 20) + (320u << 10));     // 256 KiB

    k_tr<<<16, 256, 0, stream>>>(PW, PWT);
    k_gemm<<<N_NODES / RPB, 256, 0, stream>>>(inp, W, U, V, Bias, PWT, PB,
                                              suppT, f1, f2, out);
    k_f1max<<<NHEAD, 256, 0, stream>>>(f1, f1mx);
    k_attn_mfma<<<N_NODES / TI, 1024, 0, stream>>>(adj, suppT, f1, f2, f1mx, out);
}

// Round 3
// 573.162 us; speedup vs baseline: 1.1924x; 1.1782x over previous
//
#include <hip/hip_runtime.h>
#include <hip/hip_bf16.h>

#define N_NODES 8192
#define IN_FEAT 256
#define OUT_F   64
#define NHEAD   4
#define HF      256     // NHEAD*OUT_F
#define NEG     0.2f

typedef unsigned short u16;
typedef __attribute__((ext_vector_type(8))) short short8;   // 8 bf16 (4 VGPRs)
typedef __attribute__((ext_vector_type(4))) float f32x4;    // MFMA C/D

__device__ __forceinline__ u16 f2bf(float f) {
    union { unsigned int u; float f; } v; v.f = f;
    unsigned int r = v.u + 0x7FFFu + ((v.u >> 16) & 1u);  // RNE
    return (u16)(r >> 16);
}
__device__ __forceinline__ float leaky(float x) {
    return fmaxf(x, 0.f) + NEG * fminf(x, 0.f);
}

// ---------------------------------------------------------------------------
// K0: PWT[k][c] = PW[c][k]  (256x256 fp32 transpose)
// ---------------------------------------------------------------------------
__global__ __launch_bounds__(256) void k_tr(const float* __restrict__ PW,
                                            float* __restrict__ PWT) {
    __shared__ float t[64][65];
    const int bx = (blockIdx.x & 3) * 64;   // k tile
    const int by = (blockIdx.x >> 2) * 64;  // c tile
    const int tx = threadIdx.x & 63;
    const int ty = threadIdx.x >> 6;
    #pragma unroll
    for (int r = ty; r < 64; r += 4)
        t[r][tx] = PW[(size_t)(by + r) * IN_FEAT + bx + tx];
    __syncthreads();
    #pragma unroll
    for (int r = ty; r < 64; r += 4)
        PWT[(size_t)(bx + r) * HF + by + tx] = t[tx][r];
}

// ---------------------------------------------------------------------------
// K1: per RPB rows: support = X@W -> suppT (bf16 [H*64][N]), f1/f2 head dots,
//     proj = X@PWT + proj_b + bias -> d_out (fp32).
//     RPB=4: 2048 blocks -> 8 waves/SIMD (TLP axis, untested for this kernel).
//     Per-row FMA order unchanged -> bit-identical results.
// ---------------------------------------------------------------------------
#define RPB 4
__global__ __launch_bounds__(256, 8) void k_gemm(
    const float* __restrict__ inp,   // [N, 256]
    const float* __restrict__ W,     // [256, 256] (k-major rows)
    const float* __restrict__ U,     // [H*64] flat
    const float* __restrict__ V,     // [H*64] flat
    const float* __restrict__ Bias,  // [256]
    const float* __restrict__ PWT,   // [256 k][256 c]  (transposed proj_w)
    const float* __restrict__ PB,    // [256]
    u16*   __restrict__ suppT,       // [H*64][N] bf16  (feature-major)
    float* __restrict__ f1,          // [H][N]
    float* __restrict__ f2,          // [H][N]
    float* __restrict__ outp)        // [N][256]  proj + bias + proj_b
{
    __shared__ __align__(16) float in_lds[RPB][IN_FEAT];
    const int c  = threadIdx.x;            // output column 0..255
    const int n0 = blockIdx.x * RPB;

    #pragma unroll
    for (int r = 0; r < RPB; ++r)
        in_lds[r][c] = inp[(size_t)(n0 + r) * IN_FEAT + c];
    __syncthreads();

    float accs[RPB], accp[RPB];
    #pragma unroll
    for (int r = 0; r < RPB; ++r) { accs[r] = 0.f; accp[r] = 0.f; }

    const float* wc = W   + c;
    const float* pc = PWT + c;
    float w0 = wc[0 * HF], w1 = wc[1 * HF], w2 = wc[2 * HF], w3 = wc[3 * HF];
    float p0 = pc[0 * HF], p1 = pc[1 * HF], p2 = pc[2 * HF], p3 = pc[3 * HF];

    #pragma unroll 1
    for (int k = 0; k < IN_FEAT; k += 4) {
        const int kn = (k + 4) & 255;          // wrap: last prefetch discarded
        const float nw0 = wc[(kn + 0) * HF];
        const float nw1 = wc[(kn + 1) * HF];
        const float nw2 = wc[(kn + 2) * HF];
        const float nw3 = wc[(kn + 3) * HF];
        const float np0 = pc[(kn + 0) * HF];
        const float np1 = pc[(kn + 1) * HF];
        const float np2 = pc[(kn + 2) * HF];
        const float np3 = pc[(kn + 3) * HF];
        #pragma unroll
        for (int r = 0; r < RPB; ++r) {
            const float4 xv = *(const float4*)&in_lds[r][k];
            accs[r] = fmaf(xv.x, w0, accs[r]);
            accs[r] = fmaf(xv.y, w1, accs[r]);
            accs[r] = fmaf(xv.z, w2, accs[r]);
            accs[r] = fmaf(xv.w, w3, accs[r]);
            accp[r] = fmaf(xv.x, p0, accp[r]);
            accp[r] = fmaf(xv.y, p1, accp[r]);
            accp[r] = fmaf(xv.z, p2, accp[r]);
            accp[r] = fmaf(xv.w, p3, accp[r]);
        }
        w0 = nw0; w1 = nw1; w2 = nw2; w3 = nw3;
        p0 = np0; p1 = np1; p2 = np2; p3 = np3;
    }

    const int h = c >> 6, lane = c & 63;
    const float uv = U[c], vv = V[c];
    const float bb = Bias[c] + PB[c];

    // transposed support write: one 8B store (4 rows of column c)
    union { short s[4]; unsigned long long q; } sv;
    #pragma unroll
    for (int r = 0; r < RPB; ++r) sv.s[r] = (short)f2bf(accs[r]);
    *(unsigned long long*)(suppT + (size_t)c * N_NODES + n0) = sv.q;

    #pragma unroll
    for (int r = 0; r < RPB; ++r) {
        float s1 = accs[r] * uv, s2 = accs[r] * vv;
        #pragma unroll
        for (int mm = 32; mm > 0; mm >>= 1) {
            s1 += __shfl_xor(s1, mm);
            s2 += __shfl_xor(s2, mm);
        }
        if (lane == 0) {
            f1[h * N_NODES + n0 + r] = s1;
            f2[h * N_NODES + n0 + r] = s2;
        }
        outp[(size_t)(n0 + r) * HF + c] = accp[r] + bb;
    }
}

// ---------------------------------------------------------------------------
// K2: per-head global max of f1 (upper bound for softmax shift)
// ---------------------------------------------------------------------------
__global__ __launch_bounds__(256) void k_f1max(const float* __restrict__ f1,
                                               float* __restrict__ f1max) {
    __shared__ float red[256];
    const int h = blockIdx.x;
    float m = -1e30f;
    for (int j = threadIdx.x; j < N_NODES; j += 256)
        m = fmaxf(m, f1[h * N_NODES + j]);
    red[threadIdx.x] = m;
    __syncthreads();
    for (int s = 128; s > 0; s >>= 1) {
        if (threadIdx.x < s) red[threadIdx.x] = fmaxf(red[threadIdx.x], red[threadIdx.x + s]);
        __syncthreads();
    }
    if (threadIdx.x == 0) f1max[h] = red[0];
}

// ---------------------------------------------------------------------------
// K3: MFMA attention. TI=32: block = 32-row i-tile, 16 waves = 4 heads x 4
//   j-chunks. Each wave computes TWO 16-row i-subtiles sharing the SAME B
//   fragments (B depends only on (h,j,feat)) -> suppT re-read traffic halves
//   (2 GiB -> 1 GiB). Explicit distance-1 register prefetch of B keeps 4
//   dwordx4 in flight per wave; launch_bounds(1024,4) = 128-VGPR budget
//   (round-2's forced 28 VGPR destroyed MLP).
// ---------------------------------------------------------------------------
#define TI 32
#define JSPLIT 4
#define JCHUNK (N_NODES / JSPLIT)   // 2048

union AttnSMem {
    u16   abits[TI][1026];             // 65.7 KB: nibble flags, full 8192 j
    float red[NHEAD][JSPLIT][16][65];  // 66.6 KB: chunk partial numerators
};

__global__ __launch_bounds__(1024, 4) void k_attn_mfma(
    const float* __restrict__ adj,   // [N, N] fp32
    const u16* __restrict__ suppT,   // [H*64][N] bf16 (feature-major)
    const float* __restrict__ f1,    // [H][N]
    const float* __restrict__ f2,    // [H][N]
    const float* __restrict__ f1max, // [H]
    float* __restrict__ out)         // [N][256] fp32: proj in, proj+attn out
{
    __shared__ AttnSMem sm;
    __shared__ float den[NHEAD][JSPLIT][TI];

    const int i0   = blockIdx.x * TI;
    const int tid  = threadIdx.x;
    const int wv   = tid >> 6;        // 0..15
    const int lane = tid & 63;
    const int col  = lane & 15;       // m (A) / n (B) / col (C)
    const int quad = lane >> 4;

    // ---- Phase 1: stage adjacency flags (wave wv stages rows 2wv, 2wv+1) --
    #pragma unroll
    for (int rr = 0; rr < 2; ++rr) {
        const int r = wv * 2 + rr;
        const float* ar = adj + (size_t)(i0 + r) * N_NODES;
        #pragma unroll 2
        for (int it = 0; it < 16; ++it) {
            const int j = it * 512 + lane * 8;
            const float4 a0 = *(const float4*)(ar + j);
            const float4 a1 = *(const float4*)(ar + j + 4);
            const unsigned v =
                (unsigned)(a0.x != 0.f)        | ((unsigned)(a0.y != 0.f) << 1) |
                ((unsigned)(a0.z != 0.f) << 2) | ((unsigned)(a0.w != 0.f) << 3) |
                ((unsigned)(a1.x != 0.f) << 8) | ((unsigned)(a1.y != 0.f) << 9) |
                ((unsigned)(a1.z != 0.f) << 10)| ((unsigned)(a1.w != 0.f) << 11);
            sm.abits[r][it * 64 + lane] = (u16)v;
        }
    }
    __syncthreads();

    // ---- Phase 2: flash j-loop over this wave's chunk, 2 i-subtiles ----
    const int h  = wv & 3;            // head
    const int jc = wv >> 2;           // j-chunk 0..3
    const float* f1h = f1 + (size_t)h * N_NODES;
    const float f2i0 = f2[(size_t)h * N_NODES + i0 + col];
    const float f2i1 = f2[(size_t)h * N_NODES + i0 + 16 + col];
    const float fm   = f1max[h];
    const float mi0  = leaky(fm + f2i0);                  // >= row max (sub 0)
    const float mi1  = leaky(fm + f2i1);                  // >= row max (sub 1)
    const u16* bt = suppT + (size_t)((h << 6) + col) * N_NODES; // B base row

    f32x4 acc0[4], acc1[4];
    #pragma unroll
    for (int t = 0; t < 4; ++t) {
        acc0[t] = (f32x4){0.f, 0.f, 0.f, 0.f};
        acc1[t] = (f32x4){0.f, 0.f, 0.f, 0.f};
    }
    float ls0 = 0.f, ls1 = 0.f;

    const int jb0  = jc * JCHUNK;
    const int jend = jb0 + JCHUNK;
    const int qo   = quad << 3;

    short8 bv[4];
    #pragma unroll
    for (int t = 0; t < 4; ++t)
        bv[t] = *(const short8*)(bt + (size_t)(t << 4) * N_NODES + jb0 + qo);

    #pragma unroll 1
    for (int jb = jb0; jb < jend; jb += 32) {
        const int jq = jb + qo;
        // prefetch next step's B (wrap on last iter: stays in-bounds, unused)
        const int jn = ((jb + 32 < jend) ? (jb + 32) : jb0) + qo;
        short8 bn[4];
        #pragma unroll
        for (int t = 0; t < 4; ++t)
            bn[t] = *(const short8*)(bt + (size_t)(t << 4) * N_NODES + jn);

        const float4 fa = *(const float4*)(f1h + jq);
        const float4 fb = *(const float4*)(f1h + jq + 4);
        const u16 bw0 = sm.abits[col][(jb >> 3) + quad];        // sub 0 flags
        const u16 bw1 = sm.abits[16 + col][(jb >> 3) + quad];   // sub 1 flags

        const float fj[8] = {fa.x, fa.y, fa.z, fa.w, fb.x, fb.y, fb.z, fb.w};
        union { short8 v; unsigned w[4]; } af0, af1;
        float ep0 = 0.f, ep1 = 0.f;                             // even-jj stash
        #pragma unroll
        for (int jj = 0; jj < 8; ++jj) {
            const int sh_jj = (jj & 3) + ((jj >> 2) << 3);
            const float t0 = fj[jj] + f2i0;
            const float l0 = fmaxf(t0, 0.f) + NEG * fminf(t0, 0.f);
            const float x0 = ((bw0 >> sh_jj) & 1) ? __expf(l0 - mi0) : 0.f;
            const float t1 = fj[jj] + f2i1;
            const float l1 = fmaxf(t1, 0.f) + NEG * fminf(t1, 0.f);
            const float x1 = ((bw1 >> sh_jj) & 1) ? __expf(l1 - mi1) : 0.f;
            ls0 += x0; ls1 += x1;
            if ((jj & 1) == 0) { ep0 = x0; ep1 = x1; }
            else {
                // RNE pack, bit-identical to manual f2bf
                asm("v_cvt_pk_bf16_f32 %0, %1, %2"
                    : "=v"(af0.w[jj >> 1]) : "v"(ep0), "v"(x0));
                asm("v_cvt_pk_bf16_f32 %0, %1, %2"
                    : "=v"(af1.w[jj >> 1]) : "v"(ep1), "v"(x1));
            }
        }

        #pragma unroll
        for (int t = 0; t < 4; ++t)
            acc0[t] = __builtin_amdgcn_mfma_f32_16x16x32_bf16(af0.v, bv[t], acc0[t], 0, 0, 0);
        #pragma unroll
        for (int t = 0; t < 4; ++t)
            acc1[t] = __builtin_amdgcn_mfma_f32_16x16x32_bf16(af1.v, bv[t], acc1[t], 0, 0, 0);

        #pragma unroll
        for (int t = 0; t < 4; ++t) bv[t] = bn[t];
    }

    // chunk-partial denominators: reduce over quads
    ls0 += __shfl_xor(ls0, 16);
    ls0 += __shfl_xor(ls0, 32);
    ls1 += __shfl_xor(ls1, 16);
    ls1 += __shfl_xor(ls1, 32);   // lane L holds chunk lsum for i = L&15

    // ---- Phase 3: combine chunk partials through LDS (2 subtile passes) ---
    __syncthreads();                 // all abits reads complete (red overlays)

    if (lane < 16)      den[h][jc][col]      = ls0;
    else if (lane < 32) den[h][jc][16 + col] = ls1;

    const int gid = (jc << 6) | lane;    // 0..255 within head group
    const int row = gid >> 4;            // 0..15
    const int fe  = gid & 15;

    // pass 0: subtile 0 (rows i0 .. i0+15)
    #pragma unroll
    for (int reg = 0; reg < 4; ++reg) {
        const int irow = (quad << 2) + reg;                     // C-layout row
        #pragma unroll
        for (int t = 0; t < 4; ++t)
            sm.red[h][jc][irow][(t << 4) | col] = acc0[t][reg];
    }
    __syncthreads();
    {
        const float dsum = den[h][0][row] + den[h][1][row]
                         + den[h][2][row] + den[h][3][row];
        const float inv = 1.f / dsum;
        float* op = out + (size_t)(i0 + row) * HF + (h << 6);
        #pragma unroll
        for (int ff = 0; ff < 4; ++ff) {
            const int feat = (ff << 4) | fe;
            const float s = sm.red[h][0][row][feat] + sm.red[h][1][row][feat]
                          + sm.red[h][2][row][feat] + sm.red[h][3][row][feat];
            op[feat] += s * inv;
        }
    }
    __syncthreads();

    // pass 1: subtile 1 (rows i0+16 .. i0+31)
    #pragma unroll
    for (int reg = 0; reg < 4; ++reg) {
        const int irow = (quad << 2) + reg;
        #pragma unroll
        for (int t = 0; t < 4; ++t)
            sm.red[h][jc][irow][(t << 4) | col] = acc1[t][reg];
    }
    __syncthreads();
    {
        const float dsum = den[h][0][16 + row] + den[h][1][16 + row]
                         + den[h][2][16 + row] + den[h][3][16 + row];
        const float inv = 1.f / dsum;
        float* op = out + (size_t)(i0 + 16 + row) * HF + (h << 6);
        #pragma unroll
        for (int ff = 0; ff < 4; ++ff) {
            const int feat = (ff << 4) | fe;
            const float s = sm.red[h][0][row][feat] + sm.red[h][1][row][feat]
                          + sm.red[h][2][row][feat] + sm.red[h][3][row][feat];
            op[feat] += s * inv;
        }
    }
}

// ---------------------------------------------------------------------------
extern "C" void kernel_launch(void* const* d_in, const int* in_sizes, int n_in,
                              void* d_out, int out_size, void* d_ws, size_t ws_size,
                              hipStream_t stream) {
    const float* inp  = (const float*)d_in[0];  // [8192,256]
    const float* adj  = (const float*)d_in[1];  // [8192,8192]
    const float* W    = (const float*)d_in[2];  // [256,256]
    const float* U    = (const float*)d_in[3];  // [4,64,1]
    const float* V    = (const float*)d_in[4];  // [4,64,1]
    const float* Bias = (const float*)d_in[5];  // [1,256]
    const float* PW   = (const float*)d_in[6];  // [256,256]
    const float* PB   = (const float*)d_in[7];  // [256]
    float* out = (float*)d_out;                 // [8192,256] fp32

    char* ws = (char*)d_ws;
    u16*   suppT = (u16*)(ws);                                   // 4 MiB  [H*64][N]
    float* f1    = (float*)(ws + (4u << 20));                    // 128 KiB
    float* f2    = (float*)(ws + (4u << 20) + (128u << 10));     // 128 KiB
    float* f1mx  = (float*)(ws + (4u << 20) + (256u << 10));     // 16 B
    float* PWT   = (float*)(ws + (4u << 20) + (320u << 10));     // 256 KiB

    k_tr<<<16, 256, 0, stream>>>(PW, PWT);
    k_gemm<<<N_NODES / RPB, 256, 0, stream>>>(inp, W, U, V, Bias, PWT, PB,
                                              suppT, f1, f2, out);
    k_f1max<<<NHEAD, 256, 0, stream>>>(f1, f1mx);
    k_attn_mfma<<<N_NODES / TI, 1024, 0, stream>>>(adj, suppT, f1, f2, f1mx, out);
}